// Round 3
// baseline (4305.329 us; speedup 1.0000x reference)
//
#include <hip/hip_runtime.h>
#include <hip/hip_cooperative_groups.h>

namespace cg = cooperative_groups;

static constexpr int INN  = 4096;
static constexpr int HID  = 8192;
static constexpr int OUTN = 2048;
static constexpr float LR  = 0.01f;
static constexpr float B1  = 0.9f;
static constexpr float B2  = 0.999f;
static constexpr float EPS = 1e-8f;

// ---- workspace layout (float offsets) ----
static constexpr int PH    = 0;              // [8192]  b_h + rho(x)@W1
static constexpr int HS    = PH + HID;       // [3][8192] h, mh, vh
static constexpr int OS    = HS + 3 * HID;   // [3][2048] o, mo, vo
static constexpr int RHOO  = OS + 3 * OUTN;  // [2048]   rho(o)
static constexpr int CNT   = RHOO + OUTN;    // [64]     uint counters (fallback)
static constexpr int WPART = CNT + 64;       // [512][2048] w block-partials (16B-aligned)
static constexpr int ZBASE = HS;
static constexpr int ZLEN  = WPART - HS;     // 32832 floats to zero

__device__ __forceinline__ float rho01(float v) { return fminf(fmaxf(v, 0.f), 1.f); }

// ---------------- setup: ph = b_h + rho(x)@W1 ; zero state ----------------
__global__ void __launch_bounds__(256)
k_setup(const float* __restrict__ x, const float* __restrict__ W1,
        const float* __restrict__ b_h, float* __restrict__ ws)
{
    const int t = threadIdx.x, b = blockIdx.x;
    if (b < 256) {
        __shared__ float rx[INN];
        __shared__ float red[256];
        #pragma unroll
        for (int k = 0; k < INN / 256; ++k) rx[k * 256 + t] = rho01(x[k * 256 + t]);
        __syncthreads();
        const int j  = b * 32 + (t & 31);
        const int r0 = t >> 5;
        float acc = 0.f;
        #pragma unroll 8
        for (int k = 0; k < 512; ++k) {
            const int i = r0 + 8 * k;
            acc = fmaf(rx[i], W1[(size_t)i * HID + j], acc);
        }
        red[t] = acc;
        __syncthreads();
        if (t < 32) {
            float s = 0.f;
            #pragma unroll
            for (int q = 0; q < 8; ++q) s += red[q * 32 + t];
            const int jj = b * 32 + t;
            ws[PH + jj] = s + b_h[jj];
        }
    } else {
        const int zb = b - 256;   // 0..7
        #pragma unroll
        for (int k = 0; k < 17; ++k) {
            const int idx = k * 2048 + zb * 256 + t;
            if (idx < ZLEN) ws[ZBASE + idx] = 0.f;
        }
    }
}

// ---------------- phase A: fused u = W2@rho_o + w block-partials + h-Adam ----------------
// block b owns rows [16b, 16b+16); lds = float[4*2048] (32 KB)
__device__ __forceinline__ void phase_A(const float* __restrict__ W2,
                                        float* __restrict__ ws,
                                        int b, int tid, float ub1, float ub2,
                                        float* lds)
{
    const int lane = tid & 63, wv = tid >> 6;
    const int i0 = b * 16 + wv * 4;

    const float4* ro4 = reinterpret_cast<const float4*>(ws + RHOO);
    float4 rv[8];
    #pragma unroll
    for (int k = 0; k < 8; ++k) rv[k] = ro4[lane + 64 * k];

    float* hv  = ws + HS;
    float* hm  = ws + HS + HID;
    float* hvv = ws + HS + 2 * HID;
    const float* ph = ws + PH;

    float hold[4], rh[4];
    #pragma unroll
    for (int r = 0; r < 4; ++r) { hold[r] = hv[i0 + r]; rh[r] = rho01(hold[r]); }

    float4 wacc[8];
    #pragma unroll
    for (int k = 0; k < 8; ++k) wacc[k] = make_float4(0.f, 0.f, 0.f, 0.f);
    float u[4];
    #pragma unroll
    for (int r = 0; r < 4; ++r) {
        const float4* w4 = reinterpret_cast<const float4*>(W2 + (size_t)(i0 + r) * OUTN);
        const float rhr = rh[r];
        float4 s4 = make_float4(0.f, 0.f, 0.f, 0.f);
        #pragma unroll
        for (int k = 0; k < 8; ++k) {
            const float4 a = w4[lane + 64 * k];
            s4.x = fmaf(a.x, rv[k].x, s4.x);
            s4.y = fmaf(a.y, rv[k].y, s4.y);
            s4.z = fmaf(a.z, rv[k].z, s4.z);
            s4.w = fmaf(a.w, rv[k].w, s4.w);
            wacc[k].x = fmaf(rhr, a.x, wacc[k].x);
            wacc[k].y = fmaf(rhr, a.y, wacc[k].y);
            wacc[k].z = fmaf(rhr, a.z, wacc[k].z);
            wacc[k].w = fmaf(rhr, a.w, wacc[k].w);
        }
        u[r] = (s4.x + s4.y) + (s4.z + s4.w);
    }
    #pragma unroll
    for (int r = 0; r < 4; ++r)
        #pragma unroll
        for (int off = 1; off < 64; off <<= 1) u[r] += __shfl_xor(u[r], off, 64);

    // h-Adam (state lane-uniform; lane 0 writes)
    #pragma unroll
    for (int r = 0; r < 4; ++r) {
        const int i = i0 + r;
        float h = hold[r], m = hm[i], v = hvv[i];
        const float mask = (h >= 0.f && h <= 1.f) ? 1.f : 0.f;
        const float g = h - mask * (ph[i] + u[r]);
        m = B1 * m + (1.f - B1) * g;
        v = B2 * v + (1.f - B2) * g * g;
        h -= LR * (m * ub1) / (sqrtf(v * ub2) + EPS);
        if (lane == 0) { hv[i] = h; hm[i] = m; hvv[i] = v; }
    }

    // cross-wave reduce of w partials -> WPART[b][0..2047]
    float4* wl4 = reinterpret_cast<float4*>(lds);
    #pragma unroll
    for (int k = 0; k < 8; ++k) wl4[wv * 512 + lane + 64 * k] = wacc[k];
    __syncthreads();
    float4* wp4 = reinterpret_cast<float4*>(ws + WPART);
    #pragma unroll
    for (int q = 0; q < 2; ++q) {
        const int c4 = q * 256 + tid;
        float4 s = wl4[c4];
        const float4 s1 = wl4[512 + c4], s2 = wl4[1024 + c4], s3 = wl4[1536 + c4];
        s.x += s1.x + s2.x + s3.x;
        s.y += s1.y + s2.y + s3.y;
        s.z += s1.z + s2.z + s3.z;
        s.w += s1.w + s2.w + s3.w;
        wp4[(size_t)b * 512 + c4] = s;
    }
}

// ---------------- phase B: reduce w over 512 blocks + o-Adam (block b -> cols 4b..4b+3) ----
__device__ __forceinline__ void phase_B(const float* __restrict__ b_o,
                                        float* __restrict__ ws, float* __restrict__ out,
                                        int b, int tid, float ub1, float ub2,
                                        float* lds)
{
    const float4* wp4 = reinterpret_cast<const float4*>(ws + WPART);
    float4 s  = wp4[(size_t)tid * 512 + b];
    const float4 s2 = wp4[(size_t)(tid + 256) * 512 + b];
    s.x += s2.x; s.y += s2.y; s.z += s2.z; s.w += s2.w;
    float4* r4 = reinterpret_cast<float4*>(lds);
    r4[tid] = s;
    __syncthreads();
    #pragma unroll
    for (int st = 128; st >= 1; st >>= 1) {
        if (tid < st) {
            float4 a = r4[tid], c = r4[tid + st];
            a.x += c.x; a.y += c.y; a.z += c.z; a.w += c.w;
            r4[tid] = a;
        }
        __syncthreads();
    }
    if (tid < 4) {
        const int j = b * 4 + tid;
        const float w = lds[tid];
        float* ov  = ws + OS;
        float* om  = ws + OS + OUTN;
        float* ovv = ws + OS + 2 * OUTN;
        float o = ov[j], m = om[j], v = ovv[j];
        const float mask = (o >= 0.f && o <= 1.f) ? 1.f : 0.f;
        const float g = o - mask * (b_o[j] + w);
        m = B1 * m + (1.f - B1) * g;
        v = B2 * v + (1.f - B2) * g * g;
        o -= LR * (m * ub1) / (sqrtf(v * ub2) + EPS);
        ov[j] = o; om[j] = m; ovv[j] = v;
        ws[RHOO + j] = rho01(o);
        out[j] = o;
    }
}

// ---------------- cooperative whole-loop kernel ----------------
__global__ void __launch_bounds__(256, 2)
k_loop(const float* __restrict__ W2, const float* __restrict__ b_o,
       float* __restrict__ ws, float* __restrict__ out, const int* __restrict__ nit)
{
    cg::grid_group grid = cg::this_grid();
    __shared__ float lds[4 * OUTN];
    const int b = blockIdx.x, tid = threadIdx.x;
    const int T = nit[0];
    double p1 = 1.0, p2 = 1.0;
    for (int t = 1; t <= T; ++t) {
        p1 *= (double)B1; p2 *= (double)B2;
        const float ub1 = (float)(1.0 / (1.0 - p1));
        const float ub2 = (float)(1.0 / (1.0 - p2));
        phase_A(W2, ws, b, tid, ub1, ub2, lds);
        grid.sync();
        phase_B(b_o, ws, out, b, tid, ub1, ub2, lds);
        grid.sync();
    }
}

// ---------------- fallback per-iteration kernel (atomic handoff, no coop) ----------------
__global__ void __launch_bounds__(256, 2)
k_iter(const float* __restrict__ W2, const float* __restrict__ b_o,
       float* __restrict__ ws, float* __restrict__ out,
       const int* __restrict__ nit, int t, float ub1, float ub2)
{
    if (nit[0] < t) return;
    __shared__ float lds[4 * OUTN];
    const int b = blockIdx.x, tid = threadIdx.x;
    unsigned int* cnt = reinterpret_cast<unsigned int*>(ws + CNT) + (t - 1);
    if (b < 512) {
        phase_A(W2, ws, b, tid, ub1, ub2, lds);
        __threadfence();
        __syncthreads();
        if (tid == 0) atomicAdd(cnt, 1u);
    } else {
        if (tid == 0) { while (atomicAdd(cnt, 0u) < 512u) { } }
        __syncthreads();
        __threadfence();
        phase_B(b_o, ws, out, b - 512, tid, ub1, ub2, lds);
    }
}

extern "C" void kernel_launch(void* const* d_in, const int* in_sizes, int n_in,
                              void* d_out, int out_size, void* d_ws, size_t ws_size,
                              hipStream_t stream) {
    const float* x  = (const float*)d_in[0];
    const float* W1 = (const float*)d_in[1];
    const float* W2 = (const float*)d_in[2];
    const float* bh = (const float*)d_in[3];
    const float* bo = (const float*)d_in[4];
    const int*  nit = (const int*)d_in[5];
    float* out = (float*)d_out;
    float* ws  = (float*)d_ws;

    k_setup<<<264, 256, 0, stream>>>(x, W1, bh, ws);

    void* args[] = { (void*)&W2, (void*)&bo, (void*)&ws, (void*)&out, (void*)&nit };
    hipError_t e = hipLaunchCooperativeKernel((const void*)k_loop, dim3(512), dim3(256),
                                              args, 0, stream);
    if (e != hipSuccess) {
        (void)hipGetLastError();   // clear sticky error, use fallback path
        double p1 = 1.0, p2 = 1.0;
        for (int t = 1; t <= 30; ++t) {
            p1 *= (double)B1; p2 *= (double)B2;
            const float ub1 = (float)(1.0 / (1.0 - p1));
            const float ub2 = (float)(1.0 / (1.0 - p2));
            k_iter<<<1024, 256, 0, stream>>>(W2, bo, ws, out, nit, t, ub1, ub2);
        }
    }
}

// Round 6
// 917.860 us; speedup vs baseline: 4.6906x; 4.6906x over previous
//
#include <hip/hip_runtime.h>

static constexpr int INN  = 4096;
static constexpr int HID  = 8192;
static constexpr int OUTN = 2048;
static constexpr float LR  = 0.01f;
static constexpr float B1  = 0.9f;
static constexpr float B2  = 0.999f;
static constexpr float EPS = 1e-8f;

// ---- workspace layout (float offsets) ----
static constexpr int PH    = 0;              // [8192]     b_h + rho(x)@W1
static constexpr int HS    = PH + HID;       // [3][8192]  h, mh, vh
static constexpr int OS    = HS + 3 * HID;   // [3][2048]  o, mo, vo
static constexpr int RHOO  = OS + 3 * OUTN;  // [2048]     rho(o)
static constexpr int WPART = RHOO + OUTN;    // [1024][2048] w block-partials
static constexpr int ZBASE = HS;
static constexpr int ZLEN  = WPART - HS;     // 32768 floats

__device__ __forceinline__ float rho01(float v) { return fminf(fmaxf(v, 0.f), 1.f); }

// ---------------- setup: ph = b_h + rho(x)@W1 ; zero state ----------------
__global__ void __launch_bounds__(256)
k_setup(const float* __restrict__ x, const float* __restrict__ W1,
        const float* __restrict__ b_h, float* __restrict__ ws)
{
    const int t = threadIdx.x, b = blockIdx.x;
    if (b < 256) {
        __shared__ float rx[INN];
        __shared__ float red[256];
        #pragma unroll
        for (int k = 0; k < INN / 256; ++k) rx[k * 256 + t] = rho01(x[k * 256 + t]);
        __syncthreads();
        const int j  = b * 32 + (t & 31);
        const int r0 = t >> 5;
        float acc = 0.f;
        #pragma unroll 8
        for (int k = 0; k < 512; ++k) {
            const int i = r0 + 8 * k;
            acc = fmaf(rx[i], W1[(size_t)i * HID + j], acc);
        }
        red[t] = acc;
        __syncthreads();
        if (t < 32) {
            float s = 0.f;
            #pragma unroll
            for (int q = 0; q < 8; ++q) s += red[q * 32 + t];
            const int jj = b * 32 + t;
            ws[PH + jj] = s + b_h[jj];
        }
    } else {
        const int zb = b - 256;   // 0..7
        #pragma unroll
        for (int k = 0; k < 16; ++k)
            ws[ZBASE + k * 2048 + zb * 256 + t] = 0.f;
    }
}

// ---------------- k_A: fused u = W2@rho_o + w block-partials + h-Adam ----------------
// 1024 blocks x 256 thr; block b owns rows [8b, 8b+8); each wave 2 rows.
__global__ void __launch_bounds__(256, 4)
k_A(const float* __restrict__ W2, float* __restrict__ ws,
    const int* __restrict__ nit, int t_iter, float ub1, float ub2)
{
    if (nit[0] < t_iter) return;
    __shared__ float lds[4 * OUTN];          // 32 KB: per-wave col-partials
    const int tid = threadIdx.x, b = blockIdx.x;
    const int lane = tid & 63, wv = tid >> 6;
    const int i0 = b * 8 + wv * 2;

    // rho(o): each lane holds cols 4*(lane+64k)
    const float4* ro4 = reinterpret_cast<const float4*>(ws + RHOO);
    float4 rv[8];
    #pragma unroll
    for (int k = 0; k < 8; ++k) rv[k] = ro4[lane + 64 * k];

    float* hv  = ws + HS;
    float* hm  = ws + HS + HID;
    float* hvv = ws + HS + 2 * HID;
    const float* ph = ws + PH;

    float hold[2], rh[2];
    #pragma unroll
    for (int r = 0; r < 2; ++r) { hold[r] = hv[i0 + r]; rh[r] = rho01(hold[r]); }

    float4 wacc[8];
    #pragma unroll
    for (int k = 0; k < 8; ++k) wacc[k] = make_float4(0.f, 0.f, 0.f, 0.f);
    float u[2];
    #pragma unroll
    for (int r = 0; r < 2; ++r) {
        const float4* w4 = reinterpret_cast<const float4*>(W2 + (size_t)(i0 + r) * OUTN);
        const float rhr = rh[r];
        float4 s4 = make_float4(0.f, 0.f, 0.f, 0.f);
        #pragma unroll
        for (int k = 0; k < 8; ++k) {
            const float4 a = w4[lane + 64 * k];
            s4.x = fmaf(a.x, rv[k].x, s4.x);
            s4.y = fmaf(a.y, rv[k].y, s4.y);
            s4.z = fmaf(a.z, rv[k].z, s4.z);
            s4.w = fmaf(a.w, rv[k].w, s4.w);
            wacc[k].x = fmaf(rhr, a.x, wacc[k].x);
            wacc[k].y = fmaf(rhr, a.y, wacc[k].y);
            wacc[k].z = fmaf(rhr, a.z, wacc[k].z);
            wacc[k].w = fmaf(rhr, a.w, wacc[k].w);
        }
        u[r] = (s4.x + s4.y) + (s4.z + s4.w);
    }
    #pragma unroll
    for (int r = 0; r < 2; ++r)
        #pragma unroll
        for (int off = 1; off < 64; off <<= 1) u[r] += __shfl_xor(u[r], off, 64);

    // h-Adam (state lane-uniform; lane 0 writes)
    #pragma unroll
    for (int r = 0; r < 2; ++r) {
        const int i = i0 + r;
        float h = hold[r], m = hm[i], v = hvv[i];
        const float mask = (h >= 0.f && h <= 1.f) ? 1.f : 0.f;
        const float g = h - mask * (ph[i] + u[r]);
        m = B1 * m + (1.f - B1) * g;
        v = B2 * v + (1.f - B2) * g * g;
        h -= LR * (m * ub1) / (sqrtf(v * ub2) + EPS);
        if (lane == 0) { hv[i] = h; hm[i] = m; hvv[i] = v; }
    }

    // cross-wave reduce of col-partials -> WPART[b][0..2047]
    float4* wl4 = reinterpret_cast<float4*>(lds);
    #pragma unroll
    for (int k = 0; k < 8; ++k) wl4[wv * 512 + lane + 64 * k] = wacc[k];
    __syncthreads();
    float4* wp4 = reinterpret_cast<float4*>(ws + WPART);
    #pragma unroll
    for (int q = 0; q < 2; ++q) {
        const int c4 = q * 256 + tid;
        float4 s = wl4[c4];
        const float4 s1 = wl4[512 + c4], s2 = wl4[1024 + c4], s3 = wl4[1536 + c4];
        s.x += s1.x + s2.x + s3.x;
        s.y += s1.y + s2.y + s3.y;
        s.z += s1.z + s2.z + s3.z;
        s.w += s1.w + s2.w + s3.w;
        wp4[(size_t)b * 512 + c4] = s;
    }
}

// ---------------- k_B: reduce w partials over 1024 blocks + o-Adam ----------------
// 32 blocks x 1024 thr; block b owns cols [64b, 64b+64); wave wv sums srcs [64wv,64wv+64)
__global__ void __launch_bounds__(1024)
k_B(const float* __restrict__ b_o, float* __restrict__ ws, float* __restrict__ out,
    const int* __restrict__ nit, int t_iter, float ub1, float ub2)
{
    if (nit[0] < t_iter) return;
    __shared__ float red[1024];
    const int tid = threadIdx.x, b = blockIdx.x;
    const int col = b * 64 + (tid & 63);
    const int sc  = tid >> 6;                // 0..15
    const float* wp = ws + WPART;
    float s = 0.f;
    #pragma unroll 8
    for (int k = 0; k < 64; ++k)
        s += wp[(size_t)(sc * 64 + k) * OUTN + col];
    red[tid] = s;
    __syncthreads();
    if (tid < 64) {
        float w = 0.f;
        #pragma unroll
        for (int q = 0; q < 16; ++q) w += red[q * 64 + tid];
        const int j = col;
        float* ov  = ws + OS;
        float* om  = ws + OS + OUTN;
        float* ovv = ws + OS + 2 * OUTN;
        float o = ov[j], m = om[j], v = ovv[j];
        const float mask = (o >= 0.f && o <= 1.f) ? 1.f : 0.f;
        const float g = o - mask * (b_o[j] + w);
        m = B1 * m + (1.f - B1) * g;
        v = B2 * v + (1.f - B2) * g * g;
        o -= LR * (m * ub1) / (sqrtf(v * ub2) + EPS);
        ov[j] = o; om[j] = m; ovv[j] = v;
        ws[RHOO + j] = rho01(o);
        out[j] = o;
    }
}

extern "C" void kernel_launch(void* const* d_in, const int* in_sizes, int n_in,
                              void* d_out, int out_size, void* d_ws, size_t ws_size,
                              hipStream_t stream) {
    const float* x  = (const float*)d_in[0];
    const float* W1 = (const float*)d_in[1];
    const float* W2 = (const float*)d_in[2];
    const float* bh = (const float*)d_in[3];
    const float* bo = (const float*)d_in[4];
    const int*  nit = (const int*)d_in[5];
    float* out = (float*)d_out;
    float* ws  = (float*)d_ws;

    k_setup<<<264, 256, 0, stream>>>(x, W1, bh, ws);

    double p1 = 1.0, p2 = 1.0;
    for (int t = 1; t <= 30; ++t) {
        p1 *= (double)B1; p2 *= (double)B2;
        const float ub1 = (float)(1.0 / (1.0 - p1));
        const float ub2 = (float)(1.0 / (1.0 - p2));
        k_A<<<1024, 256, 0, stream>>>(W2, ws, nit, t, ub1, ub2);
        k_B<<<32, 1024, 0, stream>>>(bo, ws, out, nit, t, ub1, ub2);
    }
}